// Round 1
// baseline (17788.260 us; speedup 1.0000x reference)
//
#include <hip/hip_runtime.h>
#include <hip/hip_cooperative_groups.h>

namespace cg = cooperative_groups;

#define T_STEPS 512
#define BATCH   32
#define FDIM    64
#define UDIM    512

// Grid: 256 WGs = 2 directions x 128 slices. Each WG owns 4 h-columns
// (=> 16 z-columns across the i,f,g,o gate blocks). R/K slices live in LDS
// for the whole kernel; c state lives in LDS; h is double-buffered in d_ws
// with one cooperative grid.sync() per time step.
// Block: 512 threads (8 waves). LDS total ~119 KB -> 1 WG/CU, 256 WGs co-resident.

__global__ __launch_bounds__(512, 1)
void lstm_bidir_kernel(const float* __restrict__ x,
                       const float* __restrict__ Kf, const float* __restrict__ Rf,
                       const float* __restrict__ bf,
                       const float* __restrict__ Kb, const float* __restrict__ Rb,
                       const float* __restrict__ bb,
                       float* __restrict__ out, float* __restrict__ ws)
{
    __shared__ __align__(16) float hs[UDIM * BATCH];   // 64KB  hs[k*32 + b]
    __shared__ __align__(16) float Rs[UDIM * 16];      // 32KB  Rs[k*16 + j]
    __shared__ __align__(16) float xs[FDIM * BATCH];   // 8KB   xs[f*32 + b]
    __shared__ __align__(16) float Ks[FDIM * 16];      // 4KB
    __shared__ __align__(16) float zpart[4 * 32 * 20]; // 10KB  [(ks*32+r)*20 + j], row padded to 20
    __shared__ __align__(16) float cbuf[4 * 32];       // cbuf[cc*32 + r]
    __shared__ __align__(16) float hout[32 * 4];       // hout[r*4 + cc]
    __shared__ float bs[16];

    const int tid = threadIdx.x;
    const int wg  = blockIdx.x;
    const int dir   = wg >> 7;     // 0 = fwd, 1 = bwd
    const int slice = wg & 127;    // 0..127
    const int colbase = slice * 4; // owned h-column base

    const float* Kg = dir ? Kb : Kf;
    const float* Rg = dir ? Rb : Rf;
    const float* bg = dir ? bb : bf;

    float* hbuf = ws + dir * (2 * UDIM * BATCH);  // [2 parities][512*32] per direction

    // ---- one-time staging: R,K,b slices into LDS ----
    for (int i = tid; i < UDIM * 16; i += 512) {
        int k = i >> 4, j = i & 15;
        int col = ((j >> 2) << 9) + colbase + (j & 3);  // gate*512 + u
        Rs[i] = Rg[k * 2048 + col];
    }
    for (int i = tid; i < FDIM * 16; i += 512) {
        int f = i >> 4, j = i & 15;
        int col = ((j >> 2) << 9) + colbase + (j & 3);
        Ks[i] = Kg[f * 2048 + col];
    }
    if (tid < 16) {
        int col = ((tid >> 2) << 9) + colbase + (tid & 3);
        bs[tid] = bg[col];
    }
    if (tid < 128) cbuf[tid] = 0.f;
    // zero parity-0 h buffers for both directions (32768 floats total, 128 per WG)
    if (tid < 128) {
        int idx = wg * 128 + tid;       // 0..32767
        int d = idx >> 14;              // /16384
        int o = idx & 16383;
        ws[d * (2 * UDIM * BATCH) + o] = 0.f;
    }

    cg::grid_group grid = cg::this_grid();
    grid.sync();

    const int r  = tid & 31;          // batch row
    const int jq = (tid >> 5) & 3;    // column quad 0..3  (j = jq*4..jq*4+3)
    const int ks = tid >> 7;          // split-k group 0..3

    int p = 0;
    #pragma unroll 1
    for (int t = 0; t < T_STEPS; ++t) {
        const int tx = dir ? (T_STEPS - 1 - t) : t;

        // stage h_prev (global -> LDS), linear float4 copy
        {
            const float4* src4 = (const float4*)(hbuf + p * (UDIM * BATCH));
            float4* hs4 = (float4*)hs;
            #pragma unroll
            for (int i = 0; i < 8; ++i) hs4[tid + i * 512] = src4[tid + i * 512];
        }
        // stage x_t transposed into xs[f][b]
        if (tid < 256) {
            int b = tid & 31, f0 = (tid >> 5) << 3;
            const float4* xg = (const float4*)(x + (size_t)b * (T_STEPS * FDIM) + tx * FDIM + f0);
            float4 v0 = xg[0], v1 = xg[1];
            xs[(f0 + 0) * 32 + b] = v0.x; xs[(f0 + 1) * 32 + b] = v0.y;
            xs[(f0 + 2) * 32 + b] = v0.z; xs[(f0 + 3) * 32 + b] = v0.w;
            xs[(f0 + 4) * 32 + b] = v1.x; xs[(f0 + 5) * 32 + b] = v1.y;
            xs[(f0 + 6) * 32 + b] = v1.z; xs[(f0 + 7) * 32 + b] = v1.w;
        }
        __syncthreads();

        // split-k GEMM: z[r][jq*4..+3] partial over k-range [ks*128, ks*128+128)
        float4 acc = make_float4(0.f, 0.f, 0.f, 0.f);
        {
            const float4* Rs4 = (const float4*)Rs;
            const int kbase = ks * 128;
            #pragma unroll 8
            for (int kk = 0; kk < 128; ++kk) {
                int k = kbase + kk;
                float hv = hs[k * 32 + r];
                float4 rv = Rs4[k * 4 + jq];
                acc.x += hv * rv.x; acc.y += hv * rv.y;
                acc.z += hv * rv.z; acc.w += hv * rv.w;
            }
            const float4* Ks4 = (const float4*)Ks;
            const int fbase = ks * 16;
            #pragma unroll
            for (int ff = 0; ff < 16; ++ff) {
                int f = fbase + ff;
                float xv = xs[f * 32 + r];
                float4 kv = Ks4[f * 4 + jq];
                acc.x += xv * kv.x; acc.y += xv * kv.y;
                acc.z += xv * kv.z; acc.w += xv * kv.w;
            }
        }
        *(float4*)&zpart[(ks * 32 + r) * 20 + jq * 4] = acc;
        __syncthreads();

        // gate phase: 128 threads, one per (r, cc) output column
        if (tid < 128) {
            int cc = tid >> 5;
            float zi = 0.f, zf = 0.f, zg = 0.f, zo = 0.f;
            #pragma unroll
            for (int s = 0; s < 4; ++s) {
                const float* zp = &zpart[(s * 32 + r) * 20];
                zi += zp[cc]; zf += zp[4 + cc]; zg += zp[8 + cc]; zo += zp[12 + cc];
            }
            zi += bs[cc]; zf += bs[4 + cc]; zg += bs[8 + cc]; zo += bs[12 + cc];
            float gi = 1.f / (1.f + __expf(-zi));
            float gf = 1.f / (1.f + __expf(-zf));
            float gg = zg / (1.f + __expf(-zg));        // swish(zg)
            float go = 1.f / (1.f + __expf(-zo));
            float c  = gf * cbuf[cc * 32 + r] + gi * gg;
            cbuf[cc * 32 + r] = c;
            float h = go * (c / (1.f + __expf(-c)));    // o * swish(c)
            hbuf[(p ^ 1) * (UDIM * BATCH) + (colbase + cc) * 32 + r] = h;
            hout[r * 4 + cc] = h;
        }
        __syncthreads();

        // output store: 32 lanes, one float4 (the WG's 4 columns) per batch row
        if (tid < 32) {
            float4 hv = *(const float4*)&hout[tid * 4];
            *(float4*)&out[(size_t)tid * (T_STEPS * 2 * UDIM) + (size_t)tx * (2 * UDIM)
                           + dir * UDIM + colbase] = hv;
        }

        grid.sync();
        p ^= 1;
    }
}

extern "C" void kernel_launch(void* const* d_in, const int* in_sizes, int n_in,
                              void* d_out, int out_size, void* d_ws, size_t ws_size,
                              hipStream_t stream) {
    const float* x  = (const float*)d_in[0];
    const float* Kf = (const float*)d_in[1];
    const float* Rf = (const float*)d_in[2];
    const float* bf = (const float*)d_in[3];
    const float* Kb = (const float*)d_in[4];
    const float* Rb = (const float*)d_in[5];
    const float* bb = (const float*)d_in[6];
    float* out = (float*)d_out;
    float* ws  = (float*)d_ws;

    void* args[] = {&x, &Kf, &Rf, &bf, &Kb, &Rb, &bb, &out, &ws};
    hipLaunchCooperativeKernel((const void*)lstm_bidir_kernel,
                               dim3(256), dim3(512), args, 0, stream);
}

// Round 2
// 4161.768 us; speedup vs baseline: 4.2742x; 4.2742x over previous
//
#include <hip/hip_runtime.h>
#include <hip/hip_cooperative_groups.h>

namespace cg = cooperative_groups;

#define T_STEPS 512
#define BATCH   32
#define FDIM    64
#define UDIM    512
#define NWG_DIR 128
#define NLEAF   8
#define LEAF_SZ 16   // 128 WGs per direction / 8 leaves

// Persistent cooperative kernel, 256 WGs = 2 dirs x 128 column-slices.
// Cross-WG h exchange via AGENT-scope relaxed atomics (LLC-coherent, no L2
// flushes). Per-step sync = custom 2-level arrival tree + flag spin, one
// fresh counter set per (dir, step). cg::grid.sync() used ONCE at init.

__global__ __launch_bounds__(512, 1)
void lstm_bidir_kernel(const float* __restrict__ x,
                       const float* __restrict__ Kf, const float* __restrict__ Rf,
                       const float* __restrict__ bf,
                       const float* __restrict__ Kb, const float* __restrict__ Rb,
                       const float* __restrict__ bb,
                       float* __restrict__ out, float* __restrict__ ws)
{
    __shared__ __align__(16) float hs[UDIM * BATCH];    // 64KB hs[k*32 + b]
    __shared__ __align__(16) float Rs[UDIM * 16];       // 32KB
    __shared__ __align__(16) float xs[2][FDIM * BATCH]; // 16KB double-buffered
    __shared__ __align__(16) float Ks[FDIM * 16];       // 4KB
    __shared__ __align__(16) float zpart[4 * 32 * 20];  // 10KB padded rows
    __shared__ __align__(16) float cbuf[4 * 32];
    __shared__ __align__(16) float hout[32 * 4];
    __shared__ float bs[16];

    const int tid = threadIdx.x;
    const int wg  = blockIdx.x;
    const int dir   = wg >> 7;
    const int slice = wg & 127;
    const int colbase = slice * 4;

    const float* Kg = dir ? Kb : Kf;
    const float* Rg = dir ? Rb : Rf;
    const float* bg = dir ? bb : bf;

    // ws layout: [2 dir][2 parity][16384] floats, then barrier ints
    float* hbase = ws;
    int* ibase   = (int*)(ws + 2 * 2 * UDIM * BATCH);   // 65536 floats in
    int* leafcnt = ibase;                                // [2][NLEAF][T_STEPS]
    int* rootcnt = ibase + 2 * NLEAF * T_STEPS;          // [2][T_STEPS]
    int* flags   = rootcnt + 2 * T_STEPS;                // [2][T_STEPS]

    const int leaf = slice & (NLEAF - 1);
    int* leaf_d = leafcnt + (dir * NLEAF + leaf) * T_STEPS;
    int* root_d = rootcnt + dir * T_STEPS;
    int* flag_d = flags   + dir * T_STEPS;

    // ---- one-time staging: R,K,b slices into LDS ----
    for (int i = tid; i < UDIM * 16; i += 512) {
        int k = i >> 4, j = i & 15;
        int col = ((j >> 2) << 9) + colbase + (j & 3);
        Rs[i] = Rg[k * 2048 + col];
    }
    for (int i = tid; i < FDIM * 16; i += 512) {
        int f = i >> 4, j = i & 15;
        int col = ((j >> 2) << 9) + colbase + (j & 3);
        Ks[i] = Kg[f * 2048 + col];
    }
    if (tid < 16) {
        int col = ((tid >> 2) << 9) + colbase + (tid & 3);
        bs[tid] = bg[col];
    }
    if (tid < 128) cbuf[tid] = 0.f;
    // zero parity-0 h buffers for both directions
    if (tid < 128) {
        int idx = wg * 128 + tid;   // 0..32767
        int d = idx >> 14;
        int o = idx & 16383;
        hbase[d * (2 * UDIM * BATCH) + o] = 0.f;
    }
    // zero barrier counters/flags (10240 ints total)
    {
        int g = wg * 512 + tid;
        if (g < 2 * NLEAF * T_STEPS + 2 * T_STEPS + 2 * T_STEPS) ibase[g] = 0;
    }

    cg::grid_group grid = cg::this_grid();
    grid.sync();   // one-time: init visible device-wide

    const int r  = tid & 31;
    const int jq = (tid >> 5) & 3;
    const int ks = tid >> 7;

    // prefetch x_0
    {
        const int tx0 = dir ? (T_STEPS - 1) : 0;
        if (tid < 256) {
            int b = tid & 31, f0 = (tid >> 5) << 3;
            const float4* xg = (const float4*)(x + (size_t)b * (T_STEPS * FDIM) + tx0 * FDIM + f0);
            float4 v0 = xg[0], v1 = xg[1];
            float* xd = xs[0];
            xd[(f0 + 0) * 32 + b] = v0.x; xd[(f0 + 1) * 32 + b] = v0.y;
            xd[(f0 + 2) * 32 + b] = v0.z; xd[(f0 + 3) * 32 + b] = v0.w;
            xd[(f0 + 4) * 32 + b] = v1.x; xd[(f0 + 5) * 32 + b] = v1.y;
            xd[(f0 + 6) * 32 + b] = v1.z; xd[(f0 + 7) * 32 + b] = v1.w;
        }
    }

    int p = 0;
    #pragma unroll 1
    for (int t = 0; t < T_STEPS; ++t) {
        const int tx = dir ? (T_STEPS - 1 - t) : t;

        // stage h_prev: AGENT-scope relaxed loads (LLC-coherent), coalesced
        {
            uint32_t* srcu = (uint32_t*)(hbase + dir * (2 * UDIM * BATCH) + p * (UDIM * BATCH));
            #pragma unroll
            for (int i = 0; i < 8; ++i) {
                uint32_t u0 = __hip_atomic_load(srcu + tid + (4*i+0) * 512, __ATOMIC_RELAXED, __HIP_MEMORY_SCOPE_AGENT);
                uint32_t u1 = __hip_atomic_load(srcu + tid + (4*i+1) * 512, __ATOMIC_RELAXED, __HIP_MEMORY_SCOPE_AGENT);
                uint32_t u2 = __hip_atomic_load(srcu + tid + (4*i+2) * 512, __ATOMIC_RELAXED, __HIP_MEMORY_SCOPE_AGENT);
                uint32_t u3 = __hip_atomic_load(srcu + tid + (4*i+3) * 512, __ATOMIC_RELAXED, __HIP_MEMORY_SCOPE_AGENT);
                hs[tid + (4*i+0) * 512] = __builtin_bit_cast(float, u0);
                hs[tid + (4*i+1) * 512] = __builtin_bit_cast(float, u1);
                hs[tid + (4*i+2) * 512] = __builtin_bit_cast(float, u2);
                hs[tid + (4*i+3) * 512] = __builtin_bit_cast(float, u3);
            }
        }
        __syncthreads();

        // split-k GEMM: z[r][jq*4..+3] over k-range [ks*128, ks*128+128)
        float4 acc = make_float4(0.f, 0.f, 0.f, 0.f);
        {
            const float4* Rs4 = (const float4*)Rs;
            const int kbase = ks * 128;
            #pragma unroll 8
            for (int kk = 0; kk < 128; ++kk) {
                int k = kbase + kk;
                float hv = hs[k * 32 + r];
                float4 rv = Rs4[k * 4 + jq];
                acc.x += hv * rv.x; acc.y += hv * rv.y;
                acc.z += hv * rv.z; acc.w += hv * rv.w;
            }
            const float4* Ks4 = (const float4*)Ks;
            const float* xsp = xs[t & 1];
            const int fbase = ks * 16;
            #pragma unroll
            for (int ff = 0; ff < 16; ++ff) {
                int f = fbase + ff;
                float xv = xsp[f * 32 + r];
                float4 kv = Ks4[f * 4 + jq];
                acc.x += xv * kv.x; acc.y += xv * kv.y;
                acc.z += xv * kv.z; acc.w += xv * kv.w;
            }
        }
        *(float4*)&zpart[(ks * 32 + r) * 20 + jq * 4] = acc;

        // prefetch x_{t+1} (independent of barrier, off critical path)
        if (t + 1 < T_STEPS && tid < 256) {
            const int txn = dir ? (T_STEPS - 2 - t) : (t + 1);
            int b = tid & 31, f0 = (tid >> 5) << 3;
            const float4* xg = (const float4*)(x + (size_t)b * (T_STEPS * FDIM) + txn * FDIM + f0);
            float4 v0 = xg[0], v1 = xg[1];
            float* xd = xs[(t + 1) & 1];
            xd[(f0 + 0) * 32 + b] = v0.x; xd[(f0 + 1) * 32 + b] = v0.y;
            xd[(f0 + 2) * 32 + b] = v0.z; xd[(f0 + 3) * 32 + b] = v0.w;
            xd[(f0 + 4) * 32 + b] = v1.x; xd[(f0 + 5) * 32 + b] = v1.y;
            xd[(f0 + 6) * 32 + b] = v1.z; xd[(f0 + 7) * 32 + b] = v1.w;
        }
        __syncthreads();

        // gate phase: 128 threads, one per (r, cc)
        if (tid < 128) {
            int cc = tid >> 5;
            float zi = 0.f, zf = 0.f, zg = 0.f, zo = 0.f;
            #pragma unroll
            for (int s = 0; s < 4; ++s) {
                const float* zp = &zpart[(s * 32 + r) * 20];
                zi += zp[cc]; zf += zp[4 + cc]; zg += zp[8 + cc]; zo += zp[12 + cc];
            }
            zi += bs[cc]; zf += bs[4 + cc]; zg += bs[8 + cc]; zo += bs[12 + cc];
            float gi = 1.f / (1.f + __expf(-zi));
            float gf = 1.f / (1.f + __expf(-zf));
            float gg = zg / (1.f + __expf(-zg));
            float go = 1.f / (1.f + __expf(-zo));
            float c  = gf * cbuf[cc * 32 + r] + gi * gg;
            cbuf[cc * 32 + r] = c;
            float h = go * (c / (1.f + __expf(-c)));
            // h exchange: AGENT-scope relaxed store (reaches LLC, no flush)
            uint32_t hu = __builtin_bit_cast(uint32_t, h);
            uint32_t* hdst = (uint32_t*)(hbase + dir * (2 * UDIM * BATCH) + (p ^ 1) * (UDIM * BATCH));
            __hip_atomic_store(hdst + (colbase + cc) * 32 + r, hu, __ATOMIC_RELAXED, __HIP_MEMORY_SCOPE_AGENT);
            hout[r * 4 + cc] = h;
        }
        __syncthreads();   // per-wave vmcnt(0) drain: h stores are at LLC after this

        // barrier arrival (skip after last step)
        if (t < T_STEPS - 1 && tid == 0) {
            asm volatile("s_waitcnt vmcnt(0)" ::: "memory");
            int old = __hip_atomic_fetch_add(&leaf_d[t], 1, __ATOMIC_RELAXED, __HIP_MEMORY_SCOPE_AGENT);
            if (old == LEAF_SZ - 1) {
                int r2 = __hip_atomic_fetch_add(&root_d[t], 1, __ATOMIC_RELAXED, __HIP_MEMORY_SCOPE_AGENT);
                if (r2 == NLEAF - 1)
                    __hip_atomic_store(&flag_d[t], 1, __ATOMIC_RELAXED, __HIP_MEMORY_SCOPE_AGENT);
            }
        }

        // output store (drains during the spin / next step)
        if (tid < 32) {
            float4 hv = *(const float4*)&hout[tid * 4];
            *(float4*)&out[(size_t)tid * (T_STEPS * 2 * UDIM) + (size_t)tx * (2 * UDIM)
                           + dir * UDIM + colbase] = hv;
        }

        // spin on flag
        if (t < T_STEPS - 1) {
            if (tid == 0) {
                while (__hip_atomic_load(&flag_d[t], __ATOMIC_RELAXED, __HIP_MEMORY_SCOPE_AGENT) == 0) {
                    __builtin_amdgcn_s_sleep(1);
                }
            }
            __syncthreads();
        }
        p ^= 1;
    }
}

extern "C" void kernel_launch(void* const* d_in, const int* in_sizes, int n_in,
                              void* d_out, int out_size, void* d_ws, size_t ws_size,
                              hipStream_t stream) {
    const float* x  = (const float*)d_in[0];
    const float* Kf = (const float*)d_in[1];
    const float* Rf = (const float*)d_in[2];
    const float* bf = (const float*)d_in[3];
    const float* Kb = (const float*)d_in[4];
    const float* Rb = (const float*)d_in[5];
    const float* bb = (const float*)d_in[6];
    float* out = (float*)d_out;
    float* ws  = (float*)d_ws;

    void* args[] = {&x, &Kf, &Rf, &bf, &Kb, &Rb, &bb, &out, &ws};
    hipLaunchCooperativeKernel((const void*)lstm_bidir_kernel,
                               dim3(256), dim3(512), args, 0, stream);
}

// Round 4
// 2449.873 us; speedup vs baseline: 7.2609x; 1.6988x over previous
//
#include <hip/hip_runtime.h>
#include <hip/hip_cooperative_groups.h>
#include <hip/hip_bf16.h>

namespace cg = cooperative_groups;

#define T_STEPS 512
#define BATCH   32
#define FDIM    64
#define UDIM    512
#define NWG_DIR 32      // WGs per direction; each owns 16 h-cols

typedef __attribute__((ext_vector_type(8))) __bf16 bf16x8;
typedef __attribute__((ext_vector_type(4))) float  f32x4;

// 64 WGs = 2 dirs x 32 slices (16 h-cols each). Per-step GEMM via
// mfma_f32_16x16x32_bf16: wave w = (Mtile = w>>2, gate = w&3) holds its 18
// R/K B-fragments in REGISTERS for the whole kernel (72 VGPRs); per k-step
// only one ds_read_b128 of the h A-frag. h exchanged through LLC as bf16,
// staged into XOR-swizzled LDS. Flat 32-arrival counter barrier per
// (dir, step). cg grid.sync() once at init.
//
// ws layout (bytes):
//   [0,      32768)  h exchange dir0 parity0   [32 rows][512 bf16] linear
//   [32768,  65536)  h exchange dir0 parity1
//   [65536,  98304)  h exchange dir1 parity0
//   [98304, 131072)  h exchange dir1 parity1
//   [131072, 135168) barrier counters int[2][T_STEPS]
// (round-3 bug: chunks were laid out at 16KB stride but are 32KB -> dir1p1
//  stores smashed the counters -> spin deadlock. Fixed here.)

__global__ __launch_bounds__(512, 2)
void lstm_bidir_kernel(const float* __restrict__ x,
                       const float* __restrict__ Kf, const float* __restrict__ Rf,
                       const float* __restrict__ bfp,
                       const float* __restrict__ Kb, const float* __restrict__ Rb,
                       const float* __restrict__ bbp,
                       float* __restrict__ out, float* __restrict__ ws)
{
    __shared__ __align__(16) unsigned char hsb[BATCH * 1024];      // 32KB bf16 h, swizzled rows
    __shared__ __align__(16) unsigned char xsb[2][BATCH * 128];    // 8KB bf16 x, swizzled rows
    __shared__ __align__(16) float zbuf[BATCH * 68];               // 8.7KB z staging
    __shared__ float cbuf[512];                                    // c state, one per (b, c)
    __shared__ float bsh[64];                                      // bias slice

    const int tid = threadIdx.x;
    const int wg  = blockIdx.x;
    const int dir   = wg >> 5;          // 0 fwd, 1 bwd
    const int slice = wg & 31;
    const int colbase = slice * 16;

    const float* Kg = dir ? Kb : Kf;
    const float* Rg = dir ? Rb : Rf;
    const float* bg = dir ? bbp : bfp;

    unsigned char* wsb = (unsigned char*)ws;
    int* cnt = (int*)(wsb + 131072);    // [2][T_STEPS]

    // ---- zero-init: parity-0 hexch (both dirs, 8192 dwords each) + counters ----
    {
        int g = wg * 512 + tid;                 // 0..32767
        if (g < 8192) {
            ((unsigned int*)wsb)[g] = 0u;                  // dir0 p0: dwords [0, 8192)
        } else if (g < 16384) {
            ((unsigned int*)wsb)[g + 8192] = 0u;           // dir1 p0: dwords [16384, 24576)
        } else if (g < 16384 + 2 * T_STEPS) {
            cnt[g - 16384] = 0;
        }
    }
    if (tid < 64) bsh[tid] = bg[(tid >> 4) * 512 + colbase + (tid & 15)];
    cbuf[tid] = 0.f;

    // ---- B-fragments (R, K slices) into registers, bf16 ----
    const int lane = tid & 63;
    const int w    = tid >> 6;      // wave 0..7
    const int mt   = w >> 2;        // M tile (batch half)
    const int gate = w & 3;         // i,f,g,o
    const int bn   = lane & 15;     // B col within tile
    const int kq   = lane >> 4;     // k quarter 0..3
    const int gcol = gate * 512 + colbase + bn;

    bf16x8 breg[18];
    #pragma unroll
    for (int s = 0; s < 16; ++s) {
        const int k0 = s * 32 + kq * 8;
        bf16x8 v;
        #pragma unroll
        for (int e = 0; e < 8; ++e)
            v[e] = (__bf16)Rg[(size_t)(k0 + e) * 2048 + gcol];
        breg[s] = v;
    }
    #pragma unroll
    for (int s = 0; s < 2; ++s) {
        const int k0 = s * 32 + kq * 8;
        bf16x8 v;
        #pragma unroll
        for (int e = 0; e < 8; ++e)
            v[e] = (__bf16)Kg[(size_t)(k0 + e) * 2048 + gcol];
        breg[16 + s] = v;
    }

    // ---- prefetch x_0 into xsb[0] (bf16, swizzled) ----
    {
        const int t0 = dir ? (T_STEPS - 1) : 0;
        if (tid < 256) {
            int b = tid >> 3, m = tid & 7;
            const float4* xg = (const float4*)(x + (size_t)b * (T_STEPS * FDIM) + (size_t)t0 * FDIM + m * 8);
            float4 v0 = xg[0], v1 = xg[1];
            unsigned int p0 = ((unsigned int)__builtin_bit_cast(unsigned short, (__bf16)v0.x)) |
                              ((unsigned int)__builtin_bit_cast(unsigned short, (__bf16)v0.y) << 16);
            unsigned int p1 = ((unsigned int)__builtin_bit_cast(unsigned short, (__bf16)v0.z)) |
                              ((unsigned int)__builtin_bit_cast(unsigned short, (__bf16)v0.w) << 16);
            unsigned int p2 = ((unsigned int)__builtin_bit_cast(unsigned short, (__bf16)v1.x)) |
                              ((unsigned int)__builtin_bit_cast(unsigned short, (__bf16)v1.y) << 16);
            unsigned int p3 = ((unsigned int)__builtin_bit_cast(unsigned short, (__bf16)v1.z)) |
                              ((unsigned int)__builtin_bit_cast(unsigned short, (__bf16)v1.w) << 16);
            uint4 pk = make_uint4(p0, p1, p2, p3);
            *(uint4*)(xsb[0] + b * 128 + (m ^ (b & 7)) * 16) = pk;
        }
    }

    cg::grid_group grid = cg::this_grid();
    grid.sync();   // init visible device-wide (once)

    int p = 0;
    #pragma unroll 1
    for (int t = 0; t < T_STEPS; ++t) {
        // ---- stage h_prev: LLC -> swizzled LDS (coalesced 8B agent loads) ----
        {
            const unsigned long long* src =
                (const unsigned long long*)(wsb + (size_t)(dir * 2 + p) * 32768);
            const int b = tid >> 4, sg = tid & 15;
            unsigned char* hrow = hsb + b * 1024;
            #pragma unroll
            for (int j = 0; j < 8; ++j) {
                unsigned long long v = __hip_atomic_load(src + b * 128 + j * 16 + sg,
                                                         __ATOMIC_RELAXED, __HIP_MEMORY_SCOPE_AGENT);
                int m  = j * 8 + (sg >> 1);
                int mp = m ^ (b & 7);
                *(unsigned long long*)(hrow + mp * 16 + (sg & 1) * 8) = v;
            }
        }
        // ---- prefetch x_{t+1} into other buffer ----
        if (t + 1 < T_STEPS && tid < 256) {
            const int tn = dir ? (T_STEPS - 2 - t) : (t + 1);
            int b = tid >> 3, m = tid & 7;
            const float4* xg = (const float4*)(x + (size_t)b * (T_STEPS * FDIM) + (size_t)tn * FDIM + m * 8);
            float4 v0 = xg[0], v1 = xg[1];
            unsigned int p0 = ((unsigned int)__builtin_bit_cast(unsigned short, (__bf16)v0.x)) |
                              ((unsigned int)__builtin_bit_cast(unsigned short, (__bf16)v0.y) << 16);
            unsigned int p1 = ((unsigned int)__builtin_bit_cast(unsigned short, (__bf16)v0.z)) |
                              ((unsigned int)__builtin_bit_cast(unsigned short, (__bf16)v0.w) << 16);
            unsigned int p2 = ((unsigned int)__builtin_bit_cast(unsigned short, (__bf16)v1.x)) |
                              ((unsigned int)__builtin_bit_cast(unsigned short, (__bf16)v1.y) << 16);
            unsigned int p3 = ((unsigned int)__builtin_bit_cast(unsigned short, (__bf16)v1.z)) |
                              ((unsigned int)__builtin_bit_cast(unsigned short, (__bf16)v1.w) << 16);
            uint4 pk = make_uint4(p0, p1, p2, p3);
            *(uint4*)(xsb[(t + 1) & 1] + b * 128 + (m ^ (b & 7)) * 16) = pk;
        }
        __syncthreads();

        // ---- MFMA: acc = h·R + x·K for this wave's (Mtile, gate) tile ----
        f32x4 acc = {0.f, 0.f, 0.f, 0.f};
        {
            const int arow = mt * 16 + bn;               // batch row (A row)
            const int inv  = arow & 7;
            const unsigned char* hrowA = hsb + arow * 1024;
            #pragma unroll
            for (int s = 0; s < 16; ++s) {
                int m = s * 4 + kq;
                bf16x8 a = *(const bf16x8*)(hrowA + ((m ^ inv) * 16));
                acc = __builtin_amdgcn_mfma_f32_16x16x32_bf16(a, breg[s], acc, 0, 0, 0);
            }
            const unsigned char* xrowA = xsb[t & 1] + arow * 128;
            #pragma unroll
            for (int s = 0; s < 2; ++s) {
                int m = s * 4 + kq;
                bf16x8 a = *(const bf16x8*)(xrowA + ((m ^ inv) * 16));
                acc = __builtin_amdgcn_mfma_f32_16x16x32_bf16(a, breg[16 + s], acc, 0, 0, 0);
            }
            // D layout: col = lane&15, row = (lane>>4)*4 + reg
            const int zb = mt * 16 + kq * 4;
            #pragma unroll
            for (int j = 0; j < 4; ++j)
                zbuf[(zb + j) * 68 + gate * 16 + bn] = acc[j];
        }
        __syncthreads();

        // ---- gates: one thread per (b, c) ----
        {
            const int b = tid >> 4, c = tid & 15;
            const float* zr = zbuf + b * 68 + c;
            float zi = zr[0]  + bsh[c];
            float zf = zr[16] + bsh[16 + c];
            float zg = zr[32] + bsh[32 + c];
            float zo = zr[48] + bsh[48 + c];
            float gi = 1.f / (1.f + __expf(-zi));
            float gf = 1.f / (1.f + __expf(-zf));
            float gg = zg / (1.f + __expf(-zg));         // swish
            float go = 1.f / (1.f + __expf(-zo));
            float cv = gf * cbuf[tid] + gi * gg;
            cbuf[tid] = cv;
            float h  = go * (cv / (1.f + __expf(-cv)));  // o * swish(c)

            const int tx = dir ? (T_STEPS - 1 - t) : t;
            out[(size_t)b * (T_STEPS * 2 * UDIM) + (size_t)tx * (2 * UDIM)
                + dir * UDIM + colbase + c] = h;

            // bf16 h -> exchange buffer (pack pairs via shfl, even-c lanes store)
            unsigned short hu = __builtin_bit_cast(unsigned short, (__bf16)h);
            int other = __shfl_xor((int)hu, 1);
            if ((c & 1) == 0) {
                unsigned int packed = (unsigned int)hu | ((unsigned int)(unsigned short)other << 16);
                unsigned int* dst = (unsigned int*)(wsb + (size_t)(dir * 2 + (p ^ 1)) * 32768);
                __hip_atomic_store(dst + b * 256 + ((colbase + c) >> 1), packed,
                                   __ATOMIC_RELAXED, __HIP_MEMORY_SCOPE_AGENT);
            }
        }
        __syncthreads();   // all waves' h stores drained (compiler vmcnt(0) before barrier)

        // ---- flat barrier: 32 arrivals per (dir, t) ----
        if (t < T_STEPS - 1) {
            if (tid == 0) {
                asm volatile("s_waitcnt vmcnt(0)" ::: "memory");
                int* c0 = &cnt[dir * T_STEPS + t];
                __hip_atomic_fetch_add(c0, 1, __ATOMIC_RELAXED, __HIP_MEMORY_SCOPE_AGENT);
                while (__hip_atomic_load(c0, __ATOMIC_RELAXED, __HIP_MEMORY_SCOPE_AGENT) < NWG_DIR)
                    __builtin_amdgcn_s_sleep(1);
            }
            __syncthreads();
        }
        p ^= 1;
    }
}

extern "C" void kernel_launch(void* const* d_in, const int* in_sizes, int n_in,
                              void* d_out, int out_size, void* d_ws, size_t ws_size,
                              hipStream_t stream) {
    (void)in_sizes; (void)n_in; (void)out_size; (void)ws_size;
    const float* x  = (const float*)d_in[0];
    const float* Kf = (const float*)d_in[1];
    const float* Rf = (const float*)d_in[2];
    const float* bf = (const float*)d_in[3];
    const float* Kb = (const float*)d_in[4];
    const float* Rb = (const float*)d_in[5];
    const float* bb = (const float*)d_in[6];
    float* out = (float*)d_out;
    float* ws  = (float*)d_ws;

    void* args[] = {&x, &Kf, &Rf, &bf, &Kb, &Rb, &bb, &out, &ws};
    hipLaunchCooperativeKernel((const void*)lstm_bidir_kernel,
                               dim3(64), dim3(512), args, 0, stream);
}

// Round 5
// 1580.116 us; speedup vs baseline: 11.2576x; 1.5504x over previous
//
#include <hip/hip_runtime.h>
#include <hip/hip_cooperative_groups.h>
#include <hip/hip_bf16.h>

namespace cg = cooperative_groups;

#define T_STEPS 512
#define BATCH   32
#define FDIM    64
#define UDIM    512
#define NWG_DIR 32      // WGs per direction; each owns 16 h-cols

typedef __attribute__((ext_vector_type(8))) __bf16 bf16x8;
typedef __attribute__((ext_vector_type(4))) float  f32x4;

// 64 WGs = 2 dirs x 32 slices (16 h-cols each). Per-step GEMM via
// mfma_f32_16x16x32_bf16 with R/K B-fragments held in registers for the
// whole kernel. h exchanged through LLC as bf16. Flat 32-arrival counter
// barrier per (dir, step). cg grid.sync() once at init.
//
// Round-5 changes (latency pipeline):
//  - h staging: 4x inline-asm global_load_dwordx4 sc0 sc1 (pipelined, ONE
//    vmcnt(0) wait) instead of 8 dependent atomic loads (was ~8 serialized
//    LLC round trips).
//  - out store deferred one step (held in register across the barrier) so
//    its drain overlaps the staging-load latency window.
//
// ws layout (bytes):
//   [0,      32768)  h exchange dir0 parity0   [32 rows][512 bf16] linear
//   [32768,  65536)  h exchange dir0 parity1
//   [65536,  98304)  h exchange dir1 parity0
//   [98304, 131072)  h exchange dir1 parity1
//   [131072, 135168) barrier counters int[2][T_STEPS]

__global__ __launch_bounds__(512, 2)
void lstm_bidir_kernel(const float* __restrict__ x,
                       const float* __restrict__ Kf, const float* __restrict__ Rf,
                       const float* __restrict__ bfp,
                       const float* __restrict__ Kb, const float* __restrict__ Rb,
                       const float* __restrict__ bbp,
                       float* __restrict__ out, float* __restrict__ ws)
{
    __shared__ __align__(16) unsigned char hsb[BATCH * 1024];      // 32KB bf16 h, swizzled rows
    __shared__ __align__(16) unsigned char xsb[2][BATCH * 128];    // 8KB bf16 x, swizzled rows
    __shared__ __align__(16) float zbuf[BATCH * 68];               // 8.7KB z staging
    __shared__ float cbuf[512];                                    // c state, one per (b, c)
    __shared__ float bsh[64];                                      // bias slice

    const int tid = threadIdx.x;
    const int wg  = blockIdx.x;
    const int dir   = wg >> 5;          // 0 fwd, 1 bwd
    const int slice = wg & 31;
    const int colbase = slice * 16;

    const float* Kg = dir ? Kb : Kf;
    const float* Rg = dir ? Rb : Rf;
    const float* bg = dir ? bbp : bfp;

    unsigned char* wsb = (unsigned char*)ws;
    int* cnt = (int*)(wsb + 131072);    // [2][T_STEPS]

    // ---- zero-init: parity-0 hexch (both dirs, 8192 dwords each) + counters ----
    {
        int g = wg * 512 + tid;                 // 0..32767
        if (g < 8192) {
            ((unsigned int*)wsb)[g] = 0u;                  // dir0 p0: dwords [0, 8192)
        } else if (g < 16384) {
            ((unsigned int*)wsb)[g + 8192] = 0u;           // dir1 p0: dwords [16384, 24576)
        } else if (g < 16384 + 2 * T_STEPS) {
            cnt[g - 16384] = 0;
        }
    }
    if (tid < 64) bsh[tid] = bg[(tid >> 4) * 512 + colbase + (tid & 15)];
    cbuf[tid] = 0.f;

    // ---- B-fragments (R, K slices) into registers, bf16 ----
    const int lane = tid & 63;
    const int w    = tid >> 6;      // wave 0..7
    const int mt   = w >> 2;        // M tile (batch half)
    const int gate = w & 3;         // i,f,g,o
    const int bn   = lane & 15;     // B col within tile
    const int kq   = lane >> 4;     // k quarter 0..3
    const int gcol = gate * 512 + colbase + bn;

    bf16x8 breg[18];
    #pragma unroll
    for (int s = 0; s < 16; ++s) {
        const int k0 = s * 32 + kq * 8;
        bf16x8 v;
        #pragma unroll
        for (int e = 0; e < 8; ++e)
            v[e] = (__bf16)Rg[(size_t)(k0 + e) * 2048 + gcol];
        breg[s] = v;
    }
    #pragma unroll
    for (int s = 0; s < 2; ++s) {
        const int k0 = s * 32 + kq * 8;
        bf16x8 v;
        #pragma unroll
        for (int e = 0; e < 8; ++e)
            v[e] = (__bf16)Kg[(size_t)(k0 + e) * 2048 + gcol];
        breg[16 + s] = v;
    }

    // ---- prefetch x_0 into xsb[0] (bf16, swizzled) ----
    {
        const int t0 = dir ? (T_STEPS - 1) : 0;
        if (tid < 256) {
            int b = tid >> 3, m = tid & 7;
            const float4* xg = (const float4*)(x + (size_t)b * (T_STEPS * FDIM) + (size_t)t0 * FDIM + m * 8);
            float4 v0 = xg[0], v1 = xg[1];
            unsigned int p0 = ((unsigned int)__builtin_bit_cast(unsigned short, (__bf16)v0.x)) |
                              ((unsigned int)__builtin_bit_cast(unsigned short, (__bf16)v0.y) << 16);
            unsigned int p1 = ((unsigned int)__builtin_bit_cast(unsigned short, (__bf16)v0.z)) |
                              ((unsigned int)__builtin_bit_cast(unsigned short, (__bf16)v0.w) << 16);
            unsigned int p2 = ((unsigned int)__builtin_bit_cast(unsigned short, (__bf16)v1.x)) |
                              ((unsigned int)__builtin_bit_cast(unsigned short, (__bf16)v1.y) << 16);
            unsigned int p3 = ((unsigned int)__builtin_bit_cast(unsigned short, (__bf16)v1.z)) |
                              ((unsigned int)__builtin_bit_cast(unsigned short, (__bf16)v1.w) << 16);
            uint4 pk = make_uint4(p0, p1, p2, p3);
            *(uint4*)(xsb[0] + b * 128 + (m ^ (b & 7)) * 16) = pk;
        }
    }

    cg::grid_group grid = cg::this_grid();
    grid.sync();   // init visible device-wide (once)

    const int bb = tid >> 4;        // batch row for staging/gates
    const int q  = tid & 15;        // col-within-slice / chunk index
    float h_keep = 0.f;

    int p = 0;
    #pragma unroll 1
    for (int t = 0; t < T_STEPS; ++t) {
        // ---- deferred out store for step t-1 (overlaps staging latency) ----
        if (t > 0) {
            const int txp = dir ? (T_STEPS - t) : (t - 1);
            out[(size_t)bb * (T_STEPS * 2 * UDIM) + (size_t)txp * (2 * UDIM)
                + dir * UDIM + colbase + q] = h_keep;
        }

        // ---- stage h_prev: 4 pipelined LLC loads -> one wait -> LDS ----
        {
            const unsigned char* srcrow = wsb + (size_t)(dir * 2 + p) * 32768 + bb * 1024;
            const int inv = bb & 7;
            uint4 r0, r1, r2, r3;
            asm volatile("global_load_dwordx4 %0, %1, off sc0 sc1"
                         : "=&v"(r0) : "v"(srcrow + (q +  0) * 16) : "memory");
            asm volatile("global_load_dwordx4 %0, %1, off sc0 sc1"
                         : "=&v"(r1) : "v"(srcrow + (q + 16) * 16) : "memory");
            asm volatile("global_load_dwordx4 %0, %1, off sc0 sc1"
                         : "=&v"(r2) : "v"(srcrow + (q + 32) * 16) : "memory");
            asm volatile("global_load_dwordx4 %0, %1, off sc0 sc1"
                         : "=&v"(r3) : "v"(srcrow + (q + 48) * 16) : "memory");

            // x_{t+1} prefetch issues inside the same vmcnt window
            if (t + 1 < T_STEPS && tid < 256) {
                const int tn = dir ? (T_STEPS - 2 - t) : (t + 1);
                int b = tid >> 3, m = tid & 7;
                const float4* xg = (const float4*)(x + (size_t)b * (T_STEPS * FDIM) + (size_t)tn * FDIM + m * 8);
                float4 v0 = xg[0], v1 = xg[1];
                unsigned int p0 = ((unsigned int)__builtin_bit_cast(unsigned short, (__bf16)v0.x)) |
                                  ((unsigned int)__builtin_bit_cast(unsigned short, (__bf16)v0.y) << 16);
                unsigned int p1 = ((unsigned int)__builtin_bit_cast(unsigned short, (__bf16)v0.z)) |
                                  ((unsigned int)__builtin_bit_cast(unsigned short, (__bf16)v0.w) << 16);
                unsigned int p2 = ((unsigned int)__builtin_bit_cast(unsigned short, (__bf16)v1.x)) |
                                  ((unsigned int)__builtin_bit_cast(unsigned short, (__bf16)v1.y) << 16);
                unsigned int p3 = ((unsigned int)__builtin_bit_cast(unsigned short, (__bf16)v1.z)) |
                                  ((unsigned int)__builtin_bit_cast(unsigned short, (__bf16)v1.w) << 16);
                uint4 pk = make_uint4(p0, p1, p2, p3);
                *(uint4*)(xsb[(t + 1) & 1] + b * 128 + (m ^ (b & 7)) * 16) = pk;
            }

            asm volatile("s_waitcnt vmcnt(0)" ::: "memory");
            __builtin_amdgcn_sched_barrier(0);

            unsigned char* hrow = hsb + bb * 1024;
            *(uint4*)(hrow + (((q +  0) ^ inv) << 4)) = r0;
            *(uint4*)(hrow + (((q + 16) ^ inv) << 4)) = r1;
            *(uint4*)(hrow + (((q + 32) ^ inv) << 4)) = r2;
            *(uint4*)(hrow + (((q + 48) ^ inv) << 4)) = r3;
        }
        __syncthreads();

        // ---- MFMA: acc = h·R + x·K for this wave's (Mtile, gate) tile ----
        f32x4 acc = {0.f, 0.f, 0.f, 0.f};
        {
            const int arow = mt * 16 + bn;               // batch row (A row)
            const int inv  = arow & 7;
            const unsigned char* hrowA = hsb + arow * 1024;
            #pragma unroll
            for (int s = 0; s < 16; ++s) {
                int m = s * 4 + kq;
                bf16x8 a = *(const bf16x8*)(hrowA + ((m ^ inv) * 16));
                acc = __builtin_amdgcn_mfma_f32_16x16x32_bf16(a, breg[s], acc, 0, 0, 0);
            }
            const unsigned char* xrowA = xsb[t & 1] + arow * 128;
            #pragma unroll
            for (int s = 0; s < 2; ++s) {
                int m = s * 4 + kq;
                bf16x8 a = *(const bf16x8*)(xrowA + ((m ^ inv) * 16));
                acc = __builtin_amdgcn_mfma_f32_16x16x32_bf16(a, breg[16 + s], acc, 0, 0, 0);
            }
            // D layout: col = lane&15, row = (lane>>4)*4 + reg
            const int zb = mt * 16 + kq * 4;
            #pragma unroll
            for (int j = 0; j < 4; ++j)
                zbuf[(zb + j) * 68 + gate * 16 + bn] = acc[j];
        }
        __syncthreads();

        // ---- gates: one thread per (b, c) ----
        {
            const float* zr = zbuf + bb * 68 + q;
            float zi = zr[0]  + bsh[q];
            float zf = zr[16] + bsh[16 + q];
            float zg = zr[32] + bsh[32 + q];
            float zo = zr[48] + bsh[48 + q];
            float gi = 1.f / (1.f + __expf(-zi));
            float gf = 1.f / (1.f + __expf(-zf));
            float gg = zg / (1.f + __expf(-zg));         // swish
            float go = 1.f / (1.f + __expf(-zo));
            float cv = gf * cbuf[tid] + gi * gg;
            cbuf[tid] = cv;
            float h  = go * (cv / (1.f + __expf(-cv)));  // o * swish(c)
            h_keep = h;                                   // out store deferred

            // bf16 h -> exchange buffer (pack pairs via shfl, even-c lanes store)
            unsigned short hu = __builtin_bit_cast(unsigned short, (__bf16)h);
            int other = __shfl_xor((int)hu, 1);
            if ((q & 1) == 0) {
                unsigned int packed = (unsigned int)hu | ((unsigned int)(unsigned short)other << 16);
                unsigned int* dst = (unsigned int*)(wsb + (size_t)(dir * 2 + (p ^ 1)) * 32768);
                __hip_atomic_store(dst + bb * 256 + ((colbase + q) >> 1), packed,
                                   __ATOMIC_RELAXED, __HIP_MEMORY_SCOPE_AGENT);
            }
        }
        __syncthreads();   // per-wave vmcnt(0) drain before barrier arrival

        // ---- flat barrier: 32 arrivals per (dir, t) ----
        if (t < T_STEPS - 1) {
            if (tid == 0) {
                asm volatile("s_waitcnt vmcnt(0)" ::: "memory");
                int* c0 = &cnt[dir * T_STEPS + t];
                __hip_atomic_fetch_add(c0, 1, __ATOMIC_RELAXED, __HIP_MEMORY_SCOPE_AGENT);
                while (__hip_atomic_load(c0, __ATOMIC_RELAXED, __HIP_MEMORY_SCOPE_AGENT) < NWG_DIR)
                    __builtin_amdgcn_s_sleep(1);
            }
            __syncthreads();
        }
        p ^= 1;
    }

    // final out store (t = T_STEPS-1)
    {
        const int txl = dir ? 0 : (T_STEPS - 1);
        out[(size_t)bb * (T_STEPS * 2 * UDIM) + (size_t)txl * (2 * UDIM)
            + dir * UDIM + colbase + q] = h_keep;
    }
}

extern "C" void kernel_launch(void* const* d_in, const int* in_sizes, int n_in,
                              void* d_out, int out_size, void* d_ws, size_t ws_size,
                              hipStream_t stream) {
    (void)in_sizes; (void)n_in; (void)out_size; (void)ws_size;
    const float* x  = (const float*)d_in[0];
    const float* Kf = (const float*)d_in[1];
    const float* Rf = (const float*)d_in[2];
    const float* bf = (const float*)d_in[3];
    const float* Kb = (const float*)d_in[4];
    const float* Rb = (const float*)d_in[5];
    const float* bb = (const float*)d_in[6];
    float* out = (float*)d_out;
    float* ws  = (float*)d_ws;

    void* args[] = {&x, &Kf, &Rf, &bf, &Kb, &Rb, &bb, &out, &ws};
    hipLaunchCooperativeKernel((const void*)lstm_bidir_kernel,
                               dim3(64), dim3(512), args, 0, stream);
}

// Round 7
// 1453.057 us; speedup vs baseline: 12.2420x; 1.0874x over previous
//
#include <hip/hip_runtime.h>
#include <hip/hip_cooperative_groups.h>
#include <hip/hip_bf16.h>

namespace cg = cooperative_groups;

#define T_STEPS 512
#define BATCH   32
#define FDIM    64
#define UDIM    512
#define NWG_DIR 32
#define SENT    0xFFFFFFFFu

typedef __attribute__((ext_vector_type(8))) __bf16 bf16x8;
typedef __attribute__((ext_vector_type(4))) float  f32x4;

// Round-7: sentinel-poll exchange (back on the proven round-5 base).
// 64 WGs = 2 dirs x 32 slices. The h exchange buffer IS the barrier:
// buffers hold bf16 h pairs per dword; a dword == 0xFFFFFFFF (NaN pair,
// unproducible by finite gate math) means "not yet written". Consumers
// poll-load their needed chunks (sc0 sc1, LLC-coherent) until sentinel-free.
// Triple buffering with lagged re-poison:
//   step t: poll buf[t%3] -> poison own slice of buf[(t+2)%3] (provably
//   consumed: h_t complete => all read h_{t-1}) -> MFMA -> gates ->
//   vmcnt(0) (orders poison < h store at LLC) -> store h_{t+1} to buf[(t+1)%3].
// Ordering proof sketch: WG i's poison drains at its step-t h-store waitcnt;
// any WG entering step t+1 observed i's h_{t+1} store, which the LLC ordered
// after i's poison => no consumer can accept stale pre-poison data.
//
// ws layout (bytes): dir d, buffer b in [0,3): chunk at (d*3+b)*32768,
// each [32 rows][512 bf16 cols] = 32KB. Total 192KB. No flags, no counters.

__global__ __launch_bounds__(512, 2)
void lstm_bidir_kernel(const float* __restrict__ x,
                       const float* __restrict__ Kf, const float* __restrict__ Rf,
                       const float* __restrict__ bfp,
                       const float* __restrict__ Kb, const float* __restrict__ Rb,
                       const float* __restrict__ bbp,
                       float* __restrict__ out, float* __restrict__ ws)
{
    __shared__ __align__(16) unsigned char hsb[BATCH * 1024];      // 32KB bf16 h, swizzled rows
    __shared__ __align__(16) unsigned char xsb[2][BATCH * 128];    // 8KB bf16 x, swizzled rows
    __shared__ __align__(16) float zbuf[BATCH * 68];               // 8.7KB z staging
    __shared__ float cbuf[512];                                    // c state, one per (b, c)
    __shared__ float bsh[64];                                      // bias slice

    const int tid = threadIdx.x;
    const int wg  = blockIdx.x;
    const int dir   = wg >> 5;          // 0 fwd, 1 bwd
    const int slice = wg & 31;
    const int colbase = slice * 16;

    const float* Kg = dir ? Kb : Kf;
    const float* Rg = dir ? Rb : Rf;
    const float* bg = dir ? bbp : bfp;

    unsigned char* wsb = (unsigned char*)ws;
    unsigned char* dirbase = wsb + (size_t)dir * 98304;   // 3 x 32KB buffers

    // ---- init: buf0 = h_0 = 0 (real), buf1/buf2 = SENTINEL; both dirs ----
    // 49152 dwords total; 32768 threads write 1-2 each.
    {
        int g = wg * 512 + tid;                       // 0..32767
        ((unsigned int*)wsb)[g] = (((g >> 13) % 3) == 0) ? 0u : SENT;
        int g2 = g + 32768;
        if (g2 < 49152)
            ((unsigned int*)wsb)[g2] = (((g2 >> 13) % 3) == 0) ? 0u : SENT;
    }
    if (tid < 64) bsh[tid] = bg[(tid >> 4) * 512 + colbase + (tid & 15)];
    cbuf[tid] = 0.f;

    // ---- B-fragments (R, K slices) into registers, bf16 ----
    const int lane = tid & 63;
    const int w    = tid >> 6;      // wave 0..7
    const int mt   = w >> 2;        // M tile (batch half)
    const int gate = w & 3;         // i,f,g,o
    const int bn   = lane & 15;     // B col within tile
    const int kq   = lane >> 4;     // k quarter 0..3
    const int gcol = gate * 512 + colbase + bn;

    bf16x8 breg[18];
    #pragma unroll
    for (int s = 0; s < 16; ++s) {
        const int k0 = s * 32 + kq * 8;
        bf16x8 v;
        #pragma unroll
        for (int e = 0; e < 8; ++e)
            v[e] = (__bf16)Rg[(size_t)(k0 + e) * 2048 + gcol];
        breg[s] = v;
    }
    #pragma unroll
    for (int s = 0; s < 2; ++s) {
        const int k0 = s * 32 + kq * 8;
        bf16x8 v;
        #pragma unroll
        for (int e = 0; e < 8; ++e)
            v[e] = (__bf16)Kg[(size_t)(k0 + e) * 2048 + gcol];
        breg[16 + s] = v;
    }

    // ---- prefetch x_0 into xsb[0] (bf16, swizzled) ----
    {
        const int t0 = dir ? (T_STEPS - 1) : 0;
        if (tid < 256) {
            int b = tid >> 3, m = tid & 7;
            const float4* xg = (const float4*)(x + (size_t)b * (T_STEPS * FDIM) + (size_t)t0 * FDIM + m * 8);
            float4 v0 = xg[0], v1 = xg[1];
            unsigned int p0 = ((unsigned int)__builtin_bit_cast(unsigned short, (__bf16)v0.x)) |
                              ((unsigned int)__builtin_bit_cast(unsigned short, (__bf16)v0.y) << 16);
            unsigned int p1 = ((unsigned int)__builtin_bit_cast(unsigned short, (__bf16)v0.z)) |
                              ((unsigned int)__builtin_bit_cast(unsigned short, (__bf16)v0.w) << 16);
            unsigned int p2 = ((unsigned int)__builtin_bit_cast(unsigned short, (__bf16)v1.x)) |
                              ((unsigned int)__builtin_bit_cast(unsigned short, (__bf16)v1.y) << 16);
            unsigned int p3 = ((unsigned int)__builtin_bit_cast(unsigned short, (__bf16)v1.z)) |
                              ((unsigned int)__builtin_bit_cast(unsigned short, (__bf16)v1.w) << 16);
            uint4 pk = make_uint4(p0, p1, p2, p3);
            *(uint4*)(xsb[0] + b * 128 + (m ^ (b & 7)) * 16) = pk;
        }
    }

    cg::grid_group grid = cg::this_grid();
    grid.sync();   // one-time: init (zeros + sentinels) visible device-wide

    const int bb = tid >> 4;        // batch row for staging/gates
    const int q  = tid & 15;        // chunk / col-within-slice index
    float h_keep = 0.f;

    #pragma unroll 1
    for (int t = 0; t < T_STEPS; ++t) {
        // ---- A: deferred out store for step t-1 (drains under the poll) ----
        if (t > 0) {
            const int txp = dir ? (T_STEPS - t) : (t - 1);
            out[(size_t)bb * (T_STEPS * 2 * UDIM) + (size_t)txp * (2 * UDIM)
                + dir * UDIM + colbase + q] = h_keep;
        }

        // ---- B: x_{t+1} raw loads (held in regs through the poll) ----
        float4 xv0, xv1;
        const bool xload = (t + 1 < T_STEPS) && (tid < 256);
        const int bxr = tid >> 3, mx = tid & 7;
        if (xload) {
            const int tn = dir ? (T_STEPS - 2 - t) : (t + 1);
            const float4* xg = (const float4*)(x + (size_t)bxr * (T_STEPS * FDIM) + (size_t)tn * FDIM + mx * 8);
            xv0 = xg[0]; xv1 = xg[1];
        }

        // ---- C: poll-load own 4 chunks of buf[t%3] until sentinel-free ----
        uint4 r0, r1, r2, r3;
        {
            const unsigned char* srcrow = dirbase + (size_t)(t % 3) * 32768 + bb * 1024;
            for (;;) {
                asm volatile("global_load_dwordx4 %0, %1, off sc0 sc1"
                             : "=&v"(r0) : "v"(srcrow + (q +  0) * 16) : "memory");
                asm volatile("global_load_dwordx4 %0, %1, off sc0 sc1"
                             : "=&v"(r1) : "v"(srcrow + (q + 16) * 16) : "memory");
                asm volatile("global_load_dwordx4 %0, %1, off sc0 sc1"
                             : "=&v"(r2) : "v"(srcrow + (q + 32) * 16) : "memory");
                asm volatile("global_load_dwordx4 %0, %1, off sc0 sc1"
                             : "=&v"(r3) : "v"(srcrow + (q + 48) * 16) : "memory");
                asm volatile("s_waitcnt vmcnt(0)" ::: "memory");
                __builtin_amdgcn_sched_barrier(0);
                unsigned bad = (r0.x == SENT) | (r0.y == SENT) | (r0.z == SENT) | (r0.w == SENT)
                             | (r1.x == SENT) | (r1.y == SENT) | (r1.z == SENT) | (r1.w == SENT)
                             | (r2.x == SENT) | (r2.y == SENT) | (r2.z == SENT) | (r2.w == SENT)
                             | (r3.x == SENT) | (r3.y == SENT) | (r3.z == SENT) | (r3.w == SENT);
                if (!bad) break;   // load RT itself is the poll backoff
            }
        }

        // ---- D: poison own slice of buf[(t+2)%3] (stale h_{t-1}, consumed) ----
        if (tid < 256) {
            int prow = tid >> 3, pd = tid & 7;
            unsigned int* pp = (unsigned int*)(dirbase + (size_t)((t + 2) % 3) * 32768
                                               + prow * 1024 + colbase * 2) + pd;
            __hip_atomic_store(pp, SENT, __ATOMIC_RELAXED, __HIP_MEMORY_SCOPE_AGENT);
        }

        // ---- E: LDS writes: h chunks (swizzled) + x_{t+1} ----
        {
            const int inv = bb & 7;
            unsigned char* hrow = hsb + bb * 1024;
            *(uint4*)(hrow + (((q +  0) ^ inv) << 4)) = r0;
            *(uint4*)(hrow + (((q + 16) ^ inv) << 4)) = r1;
            *(uint4*)(hrow + (((q + 32) ^ inv) << 4)) = r2;
            *(uint4*)(hrow + (((q + 48) ^ inv) << 4)) = r3;
        }
        if (xload) {
            unsigned int p0 = ((unsigned int)__builtin_bit_cast(unsigned short, (__bf16)xv0.x)) |
                              ((unsigned int)__builtin_bit_cast(unsigned short, (__bf16)xv0.y) << 16);
            unsigned int p1 = ((unsigned int)__builtin_bit_cast(unsigned short, (__bf16)xv0.z)) |
                              ((unsigned int)__builtin_bit_cast(unsigned short, (__bf16)xv0.w) << 16);
            unsigned int p2 = ((unsigned int)__builtin_bit_cast(unsigned short, (__bf16)xv1.x)) |
                              ((unsigned int)__builtin_bit_cast(unsigned short, (__bf16)xv1.y) << 16);
            unsigned int p3 = ((unsigned int)__builtin_bit_cast(unsigned short, (__bf16)xv1.z)) |
                              ((unsigned int)__builtin_bit_cast(unsigned short, (__bf16)xv1.w) << 16);
            uint4 pk = make_uint4(p0, p1, p2, p3);
            *(uint4*)(xsb[(t + 1) & 1] + bxr * 128 + ((mx ^ (bxr & 7)) * 16)) = pk;
        }
        __syncthreads();   // F

        // ---- G: MFMA: acc = h·R + x·K for this wave's (Mtile, gate) tile ----
        f32x4 acc = {0.f, 0.f, 0.f, 0.f};
        {
            const int arow = mt * 16 + bn;               // batch row (A row)
            const int inv  = arow & 7;
            const unsigned char* hrowA = hsb + arow * 1024;
            #pragma unroll
            for (int s = 0; s < 16; ++s) {
                int m = s * 4 + kq;
                bf16x8 a = *(const bf16x8*)(hrowA + ((m ^ inv) * 16));
                acc = __builtin_amdgcn_mfma_f32_16x16x32_bf16(a, breg[s], acc, 0, 0, 0);
            }
            const unsigned char* xrowA = xsb[t & 1] + arow * 128;
            #pragma unroll
            for (int s = 0; s < 2; ++s) {
                int m = s * 4 + kq;
                bf16x8 a = *(const bf16x8*)(xrowA + ((m ^ inv) * 16));
                acc = __builtin_amdgcn_mfma_f32_16x16x32_bf16(a, breg[16 + s], acc, 0, 0, 0);
            }
            // D layout: col = lane&15, row = (lane>>4)*4 + reg
            const int zb = mt * 16 + kq * 4;
            #pragma unroll
            for (int j = 0; j < 4; ++j)
                zbuf[(zb + j) * 68 + gate * 16 + bn] = acc[j];
        }
        __syncthreads();   // H

        // ---- I: gates + J: ordered h store ----
        {
            const float* zr = zbuf + bb * 68 + q;
            float zi = zr[0]  + bsh[q];
            float zf = zr[16] + bsh[16 + q];
            float zg = zr[32] + bsh[32 + q];
            float zo = zr[48] + bsh[48 + q];
            float gi = 1.f / (1.f + __expf(-zi));
            float gf = 1.f / (1.f + __expf(-zf));
            float gg = zg / (1.f + __expf(-zg));         // swish
            float go = 1.f / (1.f + __expf(-zo));
            float cv = gf * cbuf[tid] + gi * gg;
            cbuf[tid] = cv;
            float h  = go * (cv / (1.f + __expf(-cv)));  // o * swish(c)
            h_keep = h;                                   // out store deferred

            // pack bf16 pair via shfl; even-q lanes store one dword
            unsigned short hu = __builtin_bit_cast(unsigned short, (__bf16)h);
            int other = __shfl_xor((int)hu, 1);
            // J: ensure this wave's poison stores are at the LLC BEFORE h lands
            asm volatile("s_waitcnt vmcnt(0)" ::: "memory");
            if ((q & 1) == 0) {
                unsigned int packed = (unsigned int)hu | ((unsigned int)(unsigned short)other << 16);
                unsigned int* dst = (unsigned int*)(dirbase + (size_t)((t + 1) % 3) * 32768)
                                    + bb * 256 + ((colbase + q) >> 1);
                __hip_atomic_store(dst, packed, __ATOMIC_RELAXED, __HIP_MEMORY_SCOPE_AGENT);
            }
        }
        // no trailing barrier: next iter's LDS writes can't collide
        // (hsb/xsb writers passed H; zbuf next written only after F(t+1))
    }

    // final out store (t = T_STEPS-1)
    {
        const int txl = dir ? 0 : (T_STEPS - 1);
        out[(size_t)bb * (T_STEPS * 2 * UDIM) + (size_t)txl * (2 * UDIM)
            + dir * UDIM + colbase + q] = h_keep;
    }
}

extern "C" void kernel_launch(void* const* d_in, const int* in_sizes, int n_in,
                              void* d_out, int out_size, void* d_ws, size_t ws_size,
                              hipStream_t stream) {
    (void)in_sizes; (void)n_in; (void)out_size; (void)ws_size;
    const float* x  = (const float*)d_in[0];
    const float* Kf = (const float*)d_in[1];
    const float* Rf = (const float*)d_in[2];
    const float* bf = (const float*)d_in[3];
    const float* Kb = (const float*)d_in[4];
    const float* Rb = (const float*)d_in[5];
    const float* bb = (const float*)d_in[6];
    float* out = (float*)d_out;
    float* ws  = (float*)d_ws;

    void* args[] = {&x, &Kf, &Rf, &bf, &Kb, &Rb, &bb, &out, &ws};
    hipLaunchCooperativeKernel((const void*)lstm_bidir_kernel,
                               dim3(64), dim3(512), args, 0, stream);
}